// Round 21
// baseline (185.143 us; speedup 1.0000x reference)
//
#include <hip/hip_runtime.h>
#include <stdint.h>

typedef __attribute__((ext_vector_type(8))) short short8;
typedef __attribute__((ext_vector_type(4))) float f32x4;
typedef __attribute__((ext_vector_type(4))) unsigned short ushort4v;
typedef __attribute__((ext_vector_type(2))) unsigned int uint2v;

static __device__ __forceinline__ unsigned short f2b(float f) {
  union { float f; unsigned int u; } v; v.f = f;
  unsigned int r = v.u + 0x7FFFu + ((v.u >> 16) & 1u);
  return (unsigned short)(r >> 16);
}

static __device__ __forceinline__ float exp2fast(float x) {
#if __has_builtin(__builtin_amdgcn_exp2f)
  return __builtin_amdgcn_exp2f(x);
#else
  return exp2f(x);
#endif
}

static __device__ __forceinline__ unsigned int cvtpk(float lo, float hi) {
  unsigned int r;
  asm("v_cvt_pk_bf16_f32 %0, %1, %2" : "=v"(r) : "v"(lo), "v"(hi));
  return r;
}

// Cross-lane ^16 / ^32 reduces via permlane*_swap (VALU) - verified r5/r6.
static __device__ __forceinline__ float xor16max(float x) {
#if __has_builtin(__builtin_amdgcn_permlane16_swap)
  unsigned u = __float_as_uint(x);
  uint2v r = __builtin_amdgcn_permlane16_swap(u, u, false, false);
  return fmaxf(__uint_as_float(r[0]), __uint_as_float(r[1]));
#else
  return fmaxf(x, __shfl_xor(x, 16));
#endif
}
static __device__ __forceinline__ float xor32max(float x) {
#if __has_builtin(__builtin_amdgcn_permlane32_swap)
  unsigned u = __float_as_uint(x);
  uint2v r = __builtin_amdgcn_permlane32_swap(u, u, false, false);
  return fmaxf(__uint_as_float(r[0]), __uint_as_float(r[1]));
#else
  return fmaxf(x, __shfl_xor(x, 32));
#endif
}
static __device__ __forceinline__ float xor16add(float x) {
#if __has_builtin(__builtin_amdgcn_permlane16_swap)
  unsigned u = __float_as_uint(x);
  uint2v r = __builtin_amdgcn_permlane16_swap(u, u, false, false);
  return __uint_as_float(r[0]) + __uint_as_float(r[1]);
#else
  return x + __shfl_xor(x, 16);
#endif
}
static __device__ __forceinline__ float xor32add(float x) {
#if __has_builtin(__builtin_amdgcn_permlane32_swap)
  unsigned u = __float_as_uint(x);
  uint2v r = __builtin_amdgcn_permlane32_swap(u, u, false, false);
  return __uint_as_float(r[0]) + __uint_as_float(r[1]);
#else
  return x + __shfl_xor(x, 32);
#endif
}

static __device__ __forceinline__ void gload16(const void* g, void* l) {
  __builtin_amdgcn_global_load_lds(
      (const __attribute__((address_space(1))) unsigned int*)g,
      (__attribute__((address_space(3))) unsigned int*)l, 16, 0, 0);
}

// ---------------- fused prep: cast_x | weight transpose | rope tables ----------------

__global__ __launch_bounds__(256) void prep_kernel(
    const float* __restrict__ x, const float* __restrict__ wq,
    const float* __restrict__ wk, const float* __restrict__ wv,
    const float* __restrict__ wo, unsigned short* __restrict__ xb,
    unsigned short* __restrict__ wT, float* __restrict__ ct,
    float* __restrict__ st) {
  __shared__ float t[32][33];
  const int bid = blockIdx.x, tid = threadIdx.x;
  if (bid < 4096) {  // cast x -> bf16
    int i = (bid * 256 + tid) * 4;
    float4 v = *(const float4*)(x + i);
    ushort4v o = { f2b(v.x), f2b(v.y), f2b(v.z), f2b(v.w) };
    *(ushort4v*)(xb + i) = o;
  } else if (bid < 8192) {  // transpose+cast weights
    int tt = bid - 4096;
    int z = tt >> 10, xy = tt & 1023;
    const float* src = (z == 0) ? wq : (z == 1) ? wk : (z == 2) ? wv : wo;
    unsigned short* dst = wT + (size_t)z * 1048576;
    int tx = tid & 31, ty = tid >> 5;
    int n0 = (xy & 31) * 32, k0 = (xy >> 5) * 32;
#pragma unroll
    for (int i = 0; i < 4; ++i) {
      int r = ty + i * 8;
      t[r][tx] = src[(size_t)(k0 + r) * 1024 + n0 + tx];
    }
    __syncthreads();
#pragma unroll
    for (int i = 0; i < 4; ++i) {
      int r = ty + i * 8;
      dst[(size_t)(n0 + r) * 1024 + k0 + tx] = f2b(t[tx][r]);
    }
  } else {  // rope tables (2048*32 entries)
    int i = (bid - 8192) * 256 + tid;
    int s = i >> 5, p = i & 31;
    float ang = (float)s * powf(10000.0f, -(float)(2 * p) / 64.0f);
    ct[i] = cosf(ang);
    st[i] = sinf(ang);
  }
}

// ---------------- QKV GEMM: 128x128 tile, K64 two-panel, LDS slot-swizzled (r19) -----

__global__ __launch_bounds__(256) void gemm_kernel(
    const unsigned short* __restrict__ A, const unsigned short* __restrict__ WT,
    unsigned short* __restrict__ Qb, unsigned short* __restrict__ Kb,
    unsigned short* __restrict__ VTb,
    const float* __restrict__ ctab, const float* __restrict__ stab) {
  __shared__ unsigned short As[2][128 * 32];
  __shared__ unsigned short Bs[2][128 * 32];
  const int tid = threadIdx.x;
  const int w = tid >> 6, lane = tid & 63;
  const int m0 = blockIdx.x * 128, n0 = blockIdx.y * 128;
  const int mode = blockIdx.z;
  const unsigned short* Bt = WT + (size_t)mode * 1048576;
  const int wr = w >> 1, wc = w & 1;
  const int srow = lane >> 2, scol = lane & 3;
  const int scolx = scol ^ ((srow >> 1) & 3);          // inverse-swizzled src slot
  const int lq = lane & 15, lh = lane >> 4;
  const int slotx = (lh ^ ((lq >> 1) & 3)) * 16;       // swizzled read slot (bytes)
  f32x4 acc[4][4] = {};
  for (int k0 = 0; k0 < 1024; k0 += 64) {
#pragma unroll
    for (int p = 0; p < 2; ++p)
#pragma unroll
      for (int c = 0; c < 2; ++c) {
        int chunk = w * 2 + c;
        gload16(A + (size_t)(m0 + chunk * 16 + srow) * 1024 + k0 + p * 32 + scolx * 8,
                (char*)As[p] + chunk * 1024);
        gload16(Bt + (size_t)(n0 + chunk * 16 + srow) * 1024 + k0 + p * 32 + scolx * 8,
                (char*)Bs[p] + chunk * 1024);
      }
    __syncthreads();
#pragma unroll
    for (int p = 0; p < 2; ++p) {
      short8 af[4], bf[4];
#pragma unroll
      for (int i = 0; i < 4; ++i) {
        af[i] = *(const short8*)((const char*)As[p] +
                ((wr * 64 + i * 16 + lq) * 64 + slotx));
        bf[i] = *(const short8*)((const char*)Bs[p] +
                ((wc * 64 + i * 16 + lq) * 64 + slotx));
      }
#pragma unroll
      for (int i = 0; i < 4; ++i)
#pragma unroll
        for (int j = 0; j < 4; ++j)
          acc[i][j] = __builtin_amdgcn_mfma_f32_16x16x32_bf16(af[i], bf[j], acc[i][j], 0, 0, 0);
    }
    __syncthreads();
  }

  if (mode < 2) {
    unsigned short* dst = mode ? Kb : Qb;
    const float qscale = mode ? 1.0f : 0.125f * 1.44269504088896f;
#pragma unroll
    for (int i = 0; i < 4; ++i) {
#pragma unroll
      for (int j = 0; j < 4; ++j) {
        int n = n0 + wc * 64 + j * 16 + (lane & 15);
        int h = n >> 6, d = n & 63;
        int pairIdx = d >> 1;
        bool even = (n & 1) == 0;
#pragma unroll
        for (int r = 0; r < 4; ++r) {
          int m = m0 + wr * 64 + i * 16 + (lane >> 4) * 4 + r;
          int b = m >> 11, s = m & 2047;
          float v = acc[i][j][r];
          float pv = __shfl_xor(v, 1);
          float c = ctab[s * 32 + pairIdx], sn = stab[s * 32 + pairIdx];
          float ov = (even ? (v * c - pv * sn) : (pv * sn + v * c)) * qscale;
          dst[(size_t)((h * 2 + b) * 2048 + s) * 64 + d] = f2b(ov);
        }
      }
    }
  } else {
#pragma unroll
    for (int i = 0; i < 4; ++i) {
#pragma unroll
      for (int j = 0; j < 4; ++j) {
        int n = n0 + wc * 64 + j * 16 + (lane & 15);
        int h = n >> 6, d = n & 63;
        int mBase = m0 + wr * 64 + i * 16 + (lane >> 4) * 4;
        int b = mBase >> 11, s = mBase & 2047;
        ushort4v pk = { f2b(acc[i][j][0]), f2b(acc[i][j][1]),
                        f2b(acc[i][j][2]), f2b(acc[i][j][3]) };
        *(ushort4v*)(VTb + (size_t)((h * 2 + b) * 64 + d) * 2048 + s) = pk;
      }
    }
  }
}

// ---------------- final GEMM: 64x128 tile, 2-wave blocks, slot-swizzled, fp32 out ----

__global__ __launch_bounds__(128) void gemm_final_kernel(
    const unsigned short* __restrict__ A, const unsigned short* __restrict__ Bt,
    float* __restrict__ Fout) {
  __shared__ unsigned short As[64 * 32];
  __shared__ unsigned short Bs[128 * 32];
  const int tid = threadIdx.x;
  const int w = tid >> 6, lane = tid & 63;
  const int m0 = blockIdx.x * 64, n0 = blockIdx.y * 128;
  const int srow = lane >> 2, scol = lane & 3;
  const int scolx = scol ^ ((srow >> 1) & 3);
  const int lq = lane & 15, lh = lane >> 4;
  const int slotx = (lh ^ ((lq >> 1) & 3)) * 16;
  f32x4 acc[4][4] = {};
  for (int k0 = 0; k0 < 1024; k0 += 32) {
#pragma unroll
    for (int c = 0; c < 2; ++c) {
      int chunk = w * 2 + c;
      gload16(A + (size_t)(m0 + chunk * 16 + srow) * 1024 + k0 + scolx * 8,
              (char*)As + chunk * 1024);
    }
#pragma unroll
    for (int c = 0; c < 4; ++c) {
      int chunk = w * 4 + c;
      gload16(Bt + (size_t)(n0 + chunk * 16 + srow) * 1024 + k0 + scolx * 8,
              (char*)Bs + chunk * 1024);
    }
    __syncthreads();
    short8 af[4], bf[4];
#pragma unroll
    for (int i = 0; i < 4; ++i) {
      af[i] = *(const short8*)((const char*)As + ((i * 16 + lq) * 64 + slotx));
      bf[i] = *(const short8*)((const char*)Bs + ((w * 64 + i * 16 + lq) * 64 + slotx));
    }
#pragma unroll
    for (int i = 0; i < 4; ++i)
#pragma unroll
      for (int j = 0; j < 4; ++j)
        acc[i][j] = __builtin_amdgcn_mfma_f32_16x16x32_bf16(af[i], bf[j], acc[i][j], 0, 0, 0);
    __syncthreads();
  }
#pragma unroll
  for (int i = 0; i < 4; ++i)
#pragma unroll
    for (int j = 0; j < 4; ++j) {
      int n = n0 + w * 64 + j * 16 + (lane & 15);
#pragma unroll
      for (int r = 0; r < 4; ++r) {
        int m = m0 + i * 16 + (lane >> 4) * 4 + r;
        Fout[(size_t)m * 1024 + n] = acc[i][j][r];
      }
    }
}

// ---------------- causal flash attention: direct-L2 K/V (no staging, no barriers) ----
// m169 precedent: when K/V L2-fits, LDS staging is pure overhead. hb-clustered grid
// (r19) puts each (h,b)'s K+V (512KB) on one XCD, 4 hb/XCD = 2MB < 4MB L2. K-frags
// (16B along d) and V^T-frags (16B along s) load direct as global dwordx4. ZERO
// __syncthreads: waves fully independent. LDS = 8KB P-buffer only.

__device__ __forceinline__ void proc_tile(
    const short8 aq[2], const unsigned short* __restrict__ Khb,
    const unsigned short* __restrict__ Vhb, int kk0,
    char* Psw, int lq, int lh, int wq16, bool diag,
    float& m, float& ls, f32x4* o) {
  const int swq = (lq & 7) << 4;

  // all 8 K-fragments issued up-front: one L2-latency window
  short8 kf[8];
#pragma unroll
  for (int ct = 0; ct < 4; ++ct)
#pragma unroll
    for (int half = 0; half < 2; ++half)
      kf[ct * 2 + half] = *(const short8*)(
          Khb + (size_t)(kk0 + ct * 16 + lq) * 64 + half * 32 + lh * 8);

  f32x4 sacc[4] = {};
  __builtin_amdgcn_s_setprio(1);
#pragma unroll
  for (int ct = 0; ct < 4; ++ct) {
    sacc[ct] = __builtin_amdgcn_mfma_f32_16x16x32_bf16(kf[ct * 2], aq[0], sacc[ct], 0, 0, 0);
    sacc[ct] = __builtin_amdgcn_mfma_f32_16x16x32_bf16(kf[ct * 2 + 1], aq[1], sacc[ct], 0, 0, 0);
  }
  __builtin_amdgcn_s_setprio(0);

  // V-fragments issued now: latency hides under mask + softmax below
  short8 vf[8];
#pragma unroll
  for (int ct = 0; ct < 4; ++ct)
#pragma unroll
    for (int half = 0; half < 2; ++half)
      vf[ct * 2 + half] = *(const short8*)(
          Vhb + (size_t)(ct * 16 + lq) * 2048 + kk0 + half * 32 + lh * 8);

  if (diag) {  // mask if k_local = 16ct + 4lh + r > q_local = wq16 + lq
    int rel = wq16 + lq - 4 * lh;
#pragma unroll
    for (int ct = 0; ct < 4; ++ct)
#pragma unroll
      for (int r = 0; r < 4; ++r)
        if (ct * 16 + r > rel) sacc[ct][r] = -__builtin_inff();
  }

  float mx0 = fmaxf(fmaxf(sacc[0][0], sacc[0][1]), fmaxf(sacc[0][2], sacc[0][3]));
  float mx1 = fmaxf(fmaxf(sacc[1][0], sacc[1][1]), fmaxf(sacc[1][2], sacc[1][3]));
  float mx2 = fmaxf(fmaxf(sacc[2][0], sacc[2][1]), fmaxf(sacc[2][2], sacc[2][3]));
  float mx3 = fmaxf(fmaxf(sacc[3][0], sacc[3][1]), fmaxf(sacc[3][2], sacc[3][3]));
  float mx = fmaxf(fmaxf(mx0, mx1), fmaxf(mx2, mx3));
  mx = xor16max(mx);
  mx = xor32max(mx);
  float nm = fmaxf(m, mx);
  float al = exp2fast(m - nm);
  m = nm;
  float ps = 0.f;
#pragma unroll
  for (int ct = 0; ct < 4; ++ct)
#pragma unroll
    for (int r = 0; r < 4; ++r) {
      float p = exp2fast(sacc[ct][r] - nm);
      sacc[ct][r] = p;
      ps += p;
    }
  ls = ls * al + ps;  // per-lane partial; cross-lane reduce deferred to epilogue
#pragma unroll
  for (int ct = 0; ct < 4; ++ct)
#pragma unroll
    for (int r = 0; r < 4; ++r) o[ct][r] *= al;

  // P[q=lq][k=16ct+4lh+{0..3}] -> one b64 write per ct (4 contiguous k)
#pragma unroll
  for (int ct = 0; ct < 4; ++ct) {
    uint2v pk = { cvtpk(sacc[ct][0], sacc[ct][1]), cvtpk(sacc[ct][2], sacc[ct][3]) };
    *(uint2v*)(Psw + lq * 128 + ((ct * 32 + lh * 8) ^ swq)) = pk;
  }
  __builtin_amdgcn_wave_barrier();
  short8 pa[2];
#pragma unroll
  for (int half = 0; half < 2; ++half)
    pa[half] = *(const short8*)(Psw + lq * 128 + ((half * 64 + lh * 16) ^ swq));

  __builtin_amdgcn_s_setprio(1);
#pragma unroll
  for (int ct = 0; ct < 4; ++ct) {
    o[ct] = __builtin_amdgcn_mfma_f32_16x16x32_bf16(vf[ct * 2], pa[0], o[ct], 0, 0, 0);
    o[ct] = __builtin_amdgcn_mfma_f32_16x16x32_bf16(vf[ct * 2 + 1], pa[1], o[ct], 0, 0, 0);
  }
  __builtin_amdgcn_s_setprio(0);
}

__device__ __forceinline__ void store_o(
    const f32x4* o, float ls, char* Psw, unsigned short* __restrict__ Ob,
    int lane, int lq, int lh, int w, int qb, int h, int b) {
  float l = xor32add(xor16add(ls));  // deferred l reduction
  float invl = 1.0f / l;
#pragma unroll
  for (int ct = 0; ct < 4; ++ct)
#pragma unroll
    for (int r = 0; r < 4; ++r) {
      int d = ct * 16 + lh * 4 + r;
      *(unsigned short*)(Psw + lq * 128 + ((2 * d) ^ ((lq & 7) << 4))) =
          f2b(o[ct][r] * invl);
    }
  __builtin_amdgcn_wave_barrier();  // Psw is wave-private
#pragma unroll
  for (int pass = 0; pass < 2; ++pass) {
    int q2 = pass * 8 + (lane >> 3), d0 = (lane & 7) * 8;
    short8 vrow = *(const short8*)(Psw + q2 * 128 + ((2 * d0) ^ ((q2 & 7) << 4)));
    int s = qb + w * 16 + q2;
    *(short8*)(Ob + ((size_t)(b * 2048 + s)) * 1024 + h * 64 + d0) = vrow;
  }
  __builtin_amdgcn_wave_barrier();
}

__global__ __launch_bounds__(256) void attn_kernel(
    const unsigned short* __restrict__ Qb, const unsigned short* __restrict__ Kb,
    const unsigned short* __restrict__ VTb, unsigned short* __restrict__ Ob) {
  __shared__ unsigned short Ps[4 * 16 * 64];   // only LDS: per-wave P buffer (8KB)
  const int tid = threadIdx.x, w = tid >> 6, lane = tid & 63;
  const int hb = blockIdx.x;               // XCD-clustered: same hb -> same XCD
  const int qtL = blockIdx.y, qtH = 31 - blockIdx.y;
  const int h = hb >> 1, b = hb & 1;
  const unsigned short* Qhb = Qb + (size_t)hb * 2048 * 64;
  const unsigned short* Khb = Kb + (size_t)hb * 2048 * 64;
  const unsigned short* Vhb = VTb + (size_t)hb * 64 * 2048;
  char* Psw = (char*)Ps + w * 2048;
  const int lq = lane & 15, lh = lane >> 4;
  const int wq16 = w * 16;

  short8 aqL[2], aqH[2];
  {
    int rowL = qtL * 64 + wq16 + lq;
    int rowH = qtH * 64 + wq16 + lq;
#pragma unroll
    for (int half = 0; half < 2; ++half) {
      aqL[half] = *(const short8*)(Qhb + (size_t)rowL * 64 + half * 32 + lh * 8);
      aqH[half] = *(const short8*)(Qhb + (size_t)rowH * 64 + half * 32 + lh * 8);
    }
  }
  float mL = -__builtin_inff(), lsL = 0.f;
  float mH = -__builtin_inff(), lsH = 0.f;
  f32x4 oL[4] = {}, oH[4] = {};

  for (int kt = 0; kt <= qtH; ++kt) {
    const int kk0 = kt * 64;
    proc_tile(aqH, Khb, Vhb, kk0, Psw, lq, lh, wq16, kt == qtH, mH, lsH, oH);
    if (kt <= qtL)
      proc_tile(aqL, Khb, Vhb, kk0, Psw, lq, lh, wq16, kt == qtL, mL, lsL, oL);
  }

  store_o(oL, lsL, Psw, Ob, lane, lq, lh, w, qtL * 64, h, b);
  store_o(oH, lsH, Psw, Ob, lane, lq, lh, w, qtH * 64, h, b);
}

// ---------------- launch ----------------

extern "C" void kernel_launch(void* const* d_in, const int* in_sizes, int n_in,
                              void* d_out, int out_size, void* d_ws, size_t ws_size,
                              hipStream_t stream) {
  const float* x  = (const float*)d_in[0];
  const float* wq = (const float*)d_in[1];
  const float* wk = (const float*)d_in[2];
  const float* wv = (const float*)d_in[3];
  const float* wo = (const float*)d_in[4];
  float* out = (float*)d_out;

  char* ws = (char*)d_ws;
  const size_t SZ = 8388608;  // 8 MiB
  unsigned short* xb  = (unsigned short*)(ws);
  unsigned short* wT  = (unsigned short*)(ws + SZ);       // 4 x 2MiB (q,k,v,o)
  unsigned short* Qb  = (unsigned short*)(ws + 2 * SZ);
  unsigned short* Kb  = (unsigned short*)(ws + 3 * SZ);
  unsigned short* VTb = (unsigned short*)(ws + 4 * SZ);
  unsigned short* Ob  = (unsigned short*)(ws + 5 * SZ);
  float* ctab = (float*)(ws + 6 * SZ);
  float* stab = (float*)(ws + 6 * SZ + 262144);
  if (ws_size < 6 * SZ + 2 * 262144) return;  // ws too small: fail loudly (zeros)

  prep_kernel<<<8448, 256, 0, stream>>>(x, wq, wk, wv, wo, xb, wT, ctab, stab);
  gemm_kernel<<<dim3(32, 8, 3), 256, 0, stream>>>(xb, wT, Qb, Kb, VTb, ctab, stab);
  attn_kernel<<<dim3(32, 16), 256, 0, stream>>>(Qb, Kb, VTb, Ob);
  gemm_final_kernel<<<dim3(64, 8), 128, 0, stream>>>(Ob, wT + 3 * 1048576, out);
}

// Round 22
// 125.357 us; speedup vs baseline: 1.4769x; 1.4769x over previous
//
#include <hip/hip_runtime.h>
#include <stdint.h>

typedef __attribute__((ext_vector_type(8))) short short8;
typedef __attribute__((ext_vector_type(4))) float f32x4;
typedef __attribute__((ext_vector_type(4))) unsigned short ushort4v;
typedef __attribute__((ext_vector_type(2))) unsigned int uint2v;

static __device__ __forceinline__ unsigned short f2b(float f) {
  union { float f; unsigned int u; } v; v.f = f;
  unsigned int r = v.u + 0x7FFFu + ((v.u >> 16) & 1u);
  return (unsigned short)(r >> 16);
}

static __device__ __forceinline__ float exp2fast(float x) {
#if __has_builtin(__builtin_amdgcn_exp2f)
  return __builtin_amdgcn_exp2f(x);
#else
  return exp2f(x);
#endif
}

static __device__ __forceinline__ unsigned int cvtpk(float lo, float hi) {
  unsigned int r;
  asm("v_cvt_pk_bf16_f32 %0, %1, %2" : "=v"(r) : "v"(lo), "v"(hi));
  return r;
}

// Cross-lane ^16 / ^32 reduces via permlane*_swap (VALU) - verified r5/r6.
static __device__ __forceinline__ float xor16max(float x) {
#if __has_builtin(__builtin_amdgcn_permlane16_swap)
  unsigned u = __float_as_uint(x);
  uint2v r = __builtin_amdgcn_permlane16_swap(u, u, false, false);
  return fmaxf(__uint_as_float(r[0]), __uint_as_float(r[1]));
#else
  return fmaxf(x, __shfl_xor(x, 16));
#endif
}
static __device__ __forceinline__ float xor32max(float x) {
#if __has_builtin(__builtin_amdgcn_permlane32_swap)
  unsigned u = __float_as_uint(x);
  uint2v r = __builtin_amdgcn_permlane32_swap(u, u, false, false);
  return fmaxf(__uint_as_float(r[0]), __uint_as_float(r[1]));
#else
  return fmaxf(x, __shfl_xor(x, 32));
#endif
}
static __device__ __forceinline__ float xor16add(float x) {
#if __has_builtin(__builtin_amdgcn_permlane16_swap)
  unsigned u = __float_as_uint(x);
  uint2v r = __builtin_amdgcn_permlane16_swap(u, u, false, false);
  return __uint_as_float(r[0]) + __uint_as_float(r[1]);
#else
  return x + __shfl_xor(x, 16);
#endif
}
static __device__ __forceinline__ float xor32add(float x) {
#if __has_builtin(__builtin_amdgcn_permlane32_swap)
  unsigned u = __float_as_uint(x);
  uint2v r = __builtin_amdgcn_permlane32_swap(u, u, false, false);
  return __uint_as_float(r[0]) + __uint_as_float(r[1]);
#else
  return x + __shfl_xor(x, 32);
#endif
}

static __device__ __forceinline__ void gload16(const void* g, void* l) {
  __builtin_amdgcn_global_load_lds(
      (const __attribute__((address_space(1))) unsigned int*)g,
      (__attribute__((address_space(3))) unsigned int*)l, 16, 0, 0);
}

// ---------------- fused prep: cast_x | weight transpose | rope tables ----------------

__global__ __launch_bounds__(256) void prep_kernel(
    const float* __restrict__ x, const float* __restrict__ wq,
    const float* __restrict__ wk, const float* __restrict__ wv,
    const float* __restrict__ wo, unsigned short* __restrict__ xb,
    unsigned short* __restrict__ wT, float* __restrict__ ct,
    float* __restrict__ st) {
  __shared__ float t[32][33];
  const int bid = blockIdx.x, tid = threadIdx.x;
  if (bid < 4096) {  // cast x -> bf16
    int i = (bid * 256 + tid) * 4;
    float4 v = *(const float4*)(x + i);
    ushort4v o = { f2b(v.x), f2b(v.y), f2b(v.z), f2b(v.w) };
    *(ushort4v*)(xb + i) = o;
  } else if (bid < 8192) {  // transpose+cast weights
    int tt = bid - 4096;
    int z = tt >> 10, xy = tt & 1023;
    const float* src = (z == 0) ? wq : (z == 1) ? wk : (z == 2) ? wv : wo;
    unsigned short* dst = wT + (size_t)z * 1048576;
    int tx = tid & 31, ty = tid >> 5;
    int n0 = (xy & 31) * 32, k0 = (xy >> 5) * 32;
#pragma unroll
    for (int i = 0; i < 4; ++i) {
      int r = ty + i * 8;
      t[r][tx] = src[(size_t)(k0 + r) * 1024 + n0 + tx];
    }
    __syncthreads();
#pragma unroll
    for (int i = 0; i < 4; ++i) {
      int r = ty + i * 8;
      dst[(size_t)(n0 + r) * 1024 + k0 + tx] = f2b(t[tx][r]);
    }
  } else {  // rope tables (2048*32 entries)
    int i = (bid - 8192) * 256 + tid;
    int s = i >> 5, p = i & 31;
    float ang = (float)s * powf(10000.0f, -(float)(2 * p) / 64.0f);
    ct[i] = cosf(ang);
    st[i] = sinf(ang);
  }
}

// ---------------- QKV GEMM: 128x128 tile, K64 two-panel, LDS slot-swizzled (r19) -----
// Best measured GEMM config: stage-then-compute at K64 (co-residency beats explicit
// dbuf; r17/r18 regressed), swizzle slot' = slot ^ ((row>>1)&3) -> conflicts 0.

__global__ __launch_bounds__(256) void gemm_kernel(
    const unsigned short* __restrict__ A, const unsigned short* __restrict__ WT,
    unsigned short* __restrict__ Qb, unsigned short* __restrict__ Kb,
    unsigned short* __restrict__ VTb,
    const float* __restrict__ ctab, const float* __restrict__ stab) {
  __shared__ unsigned short As[2][128 * 32];
  __shared__ unsigned short Bs[2][128 * 32];
  const int tid = threadIdx.x;
  const int w = tid >> 6, lane = tid & 63;
  const int m0 = blockIdx.x * 128, n0 = blockIdx.y * 128;
  const int mode = blockIdx.z;
  const unsigned short* Bt = WT + (size_t)mode * 1048576;
  const int wr = w >> 1, wc = w & 1;
  const int srow = lane >> 2, scol = lane & 3;
  const int scolx = scol ^ ((srow >> 1) & 3);          // inverse-swizzled src slot
  const int lq = lane & 15, lh = lane >> 4;
  const int slotx = (lh ^ ((lq >> 1) & 3)) * 16;       // swizzled read slot (bytes)
  f32x4 acc[4][4] = {};
  for (int k0 = 0; k0 < 1024; k0 += 64) {
#pragma unroll
    for (int p = 0; p < 2; ++p)
#pragma unroll
      for (int c = 0; c < 2; ++c) {
        int chunk = w * 2 + c;
        gload16(A + (size_t)(m0 + chunk * 16 + srow) * 1024 + k0 + p * 32 + scolx * 8,
                (char*)As[p] + chunk * 1024);
        gload16(Bt + (size_t)(n0 + chunk * 16 + srow) * 1024 + k0 + p * 32 + scolx * 8,
                (char*)Bs[p] + chunk * 1024);
      }
    __syncthreads();
#pragma unroll
    for (int p = 0; p < 2; ++p) {
      short8 af[4], bf[4];
#pragma unroll
      for (int i = 0; i < 4; ++i) {
        af[i] = *(const short8*)((const char*)As[p] +
                ((wr * 64 + i * 16 + lq) * 64 + slotx));
        bf[i] = *(const short8*)((const char*)Bs[p] +
                ((wc * 64 + i * 16 + lq) * 64 + slotx));
      }
#pragma unroll
      for (int i = 0; i < 4; ++i)
#pragma unroll
        for (int j = 0; j < 4; ++j)
          acc[i][j] = __builtin_amdgcn_mfma_f32_16x16x32_bf16(af[i], bf[j], acc[i][j], 0, 0, 0);
    }
    __syncthreads();
  }

  if (mode < 2) {
    unsigned short* dst = mode ? Kb : Qb;
    const float qscale = mode ? 1.0f : 0.125f * 1.44269504088896f;
#pragma unroll
    for (int i = 0; i < 4; ++i) {
#pragma unroll
      for (int j = 0; j < 4; ++j) {
        int n = n0 + wc * 64 + j * 16 + (lane & 15);
        int h = n >> 6, d = n & 63;
        int pairIdx = d >> 1;
        bool even = (n & 1) == 0;
#pragma unroll
        for (int r = 0; r < 4; ++r) {
          int m = m0 + wr * 64 + i * 16 + (lane >> 4) * 4 + r;
          int b = m >> 11, s = m & 2047;
          float v = acc[i][j][r];
          float pv = __shfl_xor(v, 1);
          float c = ctab[s * 32 + pairIdx], sn = stab[s * 32 + pairIdx];
          float ov = (even ? (v * c - pv * sn) : (pv * sn + v * c)) * qscale;
          dst[(size_t)((h * 2 + b) * 2048 + s) * 64 + d] = f2b(ov);
        }
      }
    }
  } else {
#pragma unroll
    for (int i = 0; i < 4; ++i) {
#pragma unroll
      for (int j = 0; j < 4; ++j) {
        int n = n0 + wc * 64 + j * 16 + (lane & 15);
        int h = n >> 6, d = n & 63;
        int mBase = m0 + wr * 64 + i * 16 + (lane >> 4) * 4;
        int b = mBase >> 11, s = mBase & 2047;
        ushort4v pk = { f2b(acc[i][j][0]), f2b(acc[i][j][1]),
                        f2b(acc[i][j][2]), f2b(acc[i][j][3]) };
        *(ushort4v*)(VTb + (size_t)((h * 2 + b) * 64 + d) * 2048 + s) = pk;
      }
    }
  }
}

// ---------------- final GEMM: 64x128 tile, 2-wave blocks, slot-swizzled, fp32 out ----

__global__ __launch_bounds__(128) void gemm_final_kernel(
    const unsigned short* __restrict__ A, const unsigned short* __restrict__ Bt,
    float* __restrict__ Fout) {
  __shared__ unsigned short As[64 * 32];
  __shared__ unsigned short Bs[128 * 32];
  const int tid = threadIdx.x;
  const int w = tid >> 6, lane = tid & 63;
  const int m0 = blockIdx.x * 64, n0 = blockIdx.y * 128;
  const int srow = lane >> 2, scol = lane & 3;
  const int scolx = scol ^ ((srow >> 1) & 3);
  const int lq = lane & 15, lh = lane >> 4;
  const int slotx = (lh ^ ((lq >> 1) & 3)) * 16;
  f32x4 acc[4][4] = {};
  for (int k0 = 0; k0 < 1024; k0 += 32) {
#pragma unroll
    for (int c = 0; c < 2; ++c) {
      int chunk = w * 2 + c;
      gload16(A + (size_t)(m0 + chunk * 16 + srow) * 1024 + k0 + scolx * 8,
              (char*)As + chunk * 1024);
    }
#pragma unroll
    for (int c = 0; c < 4; ++c) {
      int chunk = w * 4 + c;
      gload16(Bt + (size_t)(n0 + chunk * 16 + srow) * 1024 + k0 + scolx * 8,
              (char*)Bs + chunk * 1024);
    }
    __syncthreads();
    short8 af[4], bf[4];
#pragma unroll
    for (int i = 0; i < 4; ++i) {
      af[i] = *(const short8*)((const char*)As + ((i * 16 + lq) * 64 + slotx));
      bf[i] = *(const short8*)((const char*)Bs + ((w * 64 + i * 16 + lq) * 64 + slotx));
    }
#pragma unroll
    for (int i = 0; i < 4; ++i)
#pragma unroll
      for (int j = 0; j < 4; ++j)
        acc[i][j] = __builtin_amdgcn_mfma_f32_16x16x32_bf16(af[i], bf[j], acc[i][j], 0, 0, 0);
    __syncthreads();
  }
#pragma unroll
  for (int i = 0; i < 4; ++i)
#pragma unroll
    for (int j = 0; j < 4; ++j) {
      int n = n0 + w * 64 + j * 16 + (lane & 15);
#pragma unroll
      for (int r = 0; r < 4; ++r) {
        int m = m0 + i * 16 + (lane >> 4) * 4 + r;
        Fout[(size_t)m * 1024 + n] = acc[i][j][r];
      }
    }
}

// ---------------- causal flash attention (r16 inner loop, hb-clustered grid) --------
// Grid (32,16): blockIdx.x = hb so the 16 q-pair blocks sharing one (h,b)'s K/V
// land on ONE XCD (id mod 8 = hb mod 8) -> per-XCD K/V set 2MB < L2. LDS staging
// via gload_lds with inverse-swizzled source (r15); direct-L2 (r21) regressed 2x.

__device__ __forceinline__ void proc_tile(
    const short8 aq[2], const unsigned short* Ksb, const unsigned short* Vsb,
    char* Psw, int lq, int lh, int wq16, bool diag,
    float& m, float& ls, f32x4* o) {
  const int swq = (lq & 7) << 4;
  f32x4 sacc[4] = {};
  __builtin_amdgcn_s_setprio(1);
#pragma unroll
  for (int ct = 0; ct < 4; ++ct) {
    const char* base = (const char*)Ksb + (ct * 16 + lq) * 128;
#pragma unroll
    for (int half = 0; half < 2; ++half) {
      short8 ak = *(const short8*)(base + ((half * 64 + lh * 16) ^ swq));
      sacc[ct] = __builtin_amdgcn_mfma_f32_16x16x32_bf16(ak, aq[half], sacc[ct], 0, 0, 0);
    }
  }
  __builtin_amdgcn_s_setprio(0);

  if (diag) {  // mask if k_local = 16ct + 4lh + r > q_local = wq16 + lq
    int rel = wq16 + lq - 4 * lh;
#pragma unroll
    for (int ct = 0; ct < 4; ++ct)
#pragma unroll
      for (int r = 0; r < 4; ++r)
        if (ct * 16 + r > rel) sacc[ct][r] = -__builtin_inff();
  }

  float mx0 = fmaxf(fmaxf(sacc[0][0], sacc[0][1]), fmaxf(sacc[0][2], sacc[0][3]));
  float mx1 = fmaxf(fmaxf(sacc[1][0], sacc[1][1]), fmaxf(sacc[1][2], sacc[1][3]));
  float mx2 = fmaxf(fmaxf(sacc[2][0], sacc[2][1]), fmaxf(sacc[2][2], sacc[2][3]));
  float mx3 = fmaxf(fmaxf(sacc[3][0], sacc[3][1]), fmaxf(sacc[3][2], sacc[3][3]));
  float mx = fmaxf(fmaxf(mx0, mx1), fmaxf(mx2, mx3));
  mx = xor16max(mx);
  mx = xor32max(mx);
  float nm = fmaxf(m, mx);
  float al = exp2fast(m - nm);
  m = nm;
  float ps = 0.f;
#pragma unroll
  for (int ct = 0; ct < 4; ++ct)
#pragma unroll
    for (int r = 0; r < 4; ++r) {
      float p = exp2fast(sacc[ct][r] - nm);
      sacc[ct][r] = p;
      ps += p;
    }
  ls = ls * al + ps;  // per-lane partial; cross-lane reduce deferred to epilogue
#pragma unroll
  for (int ct = 0; ct < 4; ++ct)
#pragma unroll
    for (int r = 0; r < 4; ++r) o[ct][r] *= al;

  // P[q=lq][k=16ct+4lh+{0..3}] -> one b64 write per ct (4 contiguous k)
#pragma unroll
  for (int ct = 0; ct < 4; ++ct) {
    uint2v pk = { cvtpk(sacc[ct][0], sacc[ct][1]), cvtpk(sacc[ct][2], sacc[ct][3]) };
    *(uint2v*)(Psw + lq * 128 + ((ct * 32 + lh * 8) ^ swq)) = pk;
  }
  __builtin_amdgcn_wave_barrier();
  short8 pa[2];
#pragma unroll
  for (int half = 0; half < 2; ++half)
    pa[half] = *(const short8*)(Psw + lq * 128 + ((half * 64 + lh * 16) ^ swq));

  __builtin_amdgcn_s_setprio(1);
#pragma unroll
  for (int ct = 0; ct < 4; ++ct) {
    const char* base = (const char*)Vsb + (ct * 16 + lq) * 128;
#pragma unroll
    for (int half = 0; half < 2; ++half) {
      short8 av = *(const short8*)(base + ((half * 64 + lh * 16) ^ swq));
      o[ct] = __builtin_amdgcn_mfma_f32_16x16x32_bf16(av, pa[half], o[ct], 0, 0, 0);
    }
  }
  __builtin_amdgcn_s_setprio(0);
}

__device__ __forceinline__ void store_o(
    const f32x4* o, float ls, char* Psw, unsigned short* __restrict__ Ob,
    int lane, int lq, int lh, int w, int qb, int h, int b) {
  float l = xor32add(xor16add(ls));  // deferred l reduction
  float invl = 1.0f / l;
#pragma unroll
  for (int ct = 0; ct < 4; ++ct)
#pragma unroll
    for (int r = 0; r < 4; ++r) {
      int d = ct * 16 + lh * 4 + r;
      *(unsigned short*)(Psw + lq * 128 + ((2 * d) ^ ((lq & 7) << 4))) =
          f2b(o[ct][r] * invl);
    }
  __builtin_amdgcn_wave_barrier();  // Psw is wave-private
#pragma unroll
  for (int pass = 0; pass < 2; ++pass) {
    int q2 = pass * 8 + (lane >> 3), d0 = (lane & 7) * 8;
    short8 vrow = *(const short8*)(Psw + q2 * 128 + ((2 * d0) ^ ((q2 & 7) << 4)));
    int s = qb + w * 16 + q2;
    *(short8*)(Ob + ((size_t)(b * 2048 + s)) * 1024 + h * 64 + d0) = vrow;
  }
  __builtin_amdgcn_wave_barrier();
}

__global__ __launch_bounds__(256) void attn_kernel(
    const unsigned short* __restrict__ Qb, const unsigned short* __restrict__ Kb,
    const unsigned short* __restrict__ VTb, unsigned short* __restrict__ Ob) {
  __shared__ unsigned short Ks[2][64 * 64];
  __shared__ unsigned short Vs[2][64 * 64];
  __shared__ unsigned short Ps[4 * 16 * 64];
  const int tid = threadIdx.x, w = tid >> 6, lane = tid & 63;
  const int hb = blockIdx.x;               // XCD-clustered: same hb -> same XCD
  const int qtL = blockIdx.y, qtH = 31 - blockIdx.y;
  const int h = hb >> 1, b = hb & 1;
  const unsigned short* Qhb = Qb + (size_t)hb * 2048 * 64;
  const unsigned short* Khb = Kb + (size_t)hb * 2048 * 64;
  const unsigned short* Vhb = VTb + (size_t)hb * 64 * 2048;
  char* Psw = (char*)Ps + w * 2048;
  const int lq = lane & 15, lh = lane >> 4;
  const int wq16 = w * 16;

  short8 aqL[2], aqH[2];
  {
    int rowL = qtL * 64 + wq16 + lq;
    int rowH = qtH * 64 + wq16 + lq;
#pragma unroll
    for (int half = 0; half < 2; ++half) {
      aqL[half] = *(const short8*)(Qhb + (size_t)rowL * 64 + half * 32 + lh * 8);
      aqH[half] = *(const short8*)(Qhb + (size_t)rowH * 64 + half * 32 + lh * 8);
    }
  }
  float mL = -__builtin_inff(), lsL = 0.f;
  float mH = -__builtin_inff(), lsH = 0.f;
  f32x4 oL[4] = {}, oH[4] = {};

  // gload_lds staging: wave fills linear bytes [w*1024, +1024) and [4096+w*1024);
  // inverse-swizzled per-lane source columns preserve the XOR-swizzled image.
  const int a0 = w * 1024 + lane * 16;
  const int a1 = a0 + 4096;
  const int sr0 = a0 >> 7, sr1 = a1 >> 7;
  const int se0 = ((a0 & 127) ^ ((sr0 & 7) << 4)) >> 1;
  const int se1 = ((a1 & 127) ^ ((sr1 & 7) << 4)) >> 1;

#define STAGE_TILE(buf, kk0)                                                      \
  do {                                                                            \
    gload16(Khb + (size_t)((kk0) + sr0) * 64 + se0, (char*)Ks[buf] + w * 1024);   \
    gload16(Khb + (size_t)((kk0) + sr1) * 64 + se1,                               \
            (char*)Ks[buf] + 4096 + w * 1024);                                    \
    gload16(Vhb + (size_t)sr0 * 2048 + (kk0) + se0, (char*)Vs[buf] + w * 1024);   \
    gload16(Vhb + (size_t)sr1 * 2048 + (kk0) + se1,                               \
            (char*)Vs[buf] + 4096 + w * 1024);                                    \
  } while (0)

  STAGE_TILE(0, 0);
  __syncthreads();  // compiler drains vmcnt before barrier -> tile 0 ready

  for (int kt = 0; kt <= qtH; ++kt) {
    const int cur = kt & 1;
    if (kt < qtH) STAGE_TILE(cur ^ 1, (kt + 1) * 64);  // async into idle buffer
    proc_tile(aqH, Ks[cur], Vs[cur], Psw, lq, lh, wq16, kt == qtH, mH, lsH, oH);
    if (kt <= qtL)
      proc_tile(aqL, Ks[cur], Vs[cur], Psw, lq, lh, wq16, kt == qtL, mL, lsL, oL);
    __syncthreads();  // drains gloads; next iter reads cur^1
  }
#undef STAGE_TILE

  store_o(oL, lsL, Psw, Ob, lane, lq, lh, w, qtL * 64, h, b);
  store_o(oH, lsH, Psw, Ob, lane, lq, lh, w, qtH * 64, h, b);
}

// ---------------- launch ----------------

extern "C" void kernel_launch(void* const* d_in, const int* in_sizes, int n_in,
                              void* d_out, int out_size, void* d_ws, size_t ws_size,
                              hipStream_t stream) {
  const float* x  = (const float*)d_in[0];
  const float* wq = (const float*)d_in[1];
  const float* wk = (const float*)d_in[2];
  const float* wv = (const float*)d_in[3];
  const float* wo = (const float*)d_in[4];
  float* out = (float*)d_out;

  char* ws = (char*)d_ws;
  const size_t SZ = 8388608;  // 8 MiB
  unsigned short* xb  = (unsigned short*)(ws);
  unsigned short* wT  = (unsigned short*)(ws + SZ);       // 4 x 2MiB (q,k,v,o)
  unsigned short* Qb  = (unsigned short*)(ws + 2 * SZ);
  unsigned short* Kb  = (unsigned short*)(ws + 3 * SZ);
  unsigned short* VTb = (unsigned short*)(ws + 4 * SZ);
  unsigned short* Ob  = (unsigned short*)(ws + 5 * SZ);
  float* ctab = (float*)(ws + 6 * SZ);
  float* stab = (float*)(ws + 6 * SZ + 262144);
  if (ws_size < 6 * SZ + 2 * 262144) return;  // ws too small: fail loudly (zeros)

  prep_kernel<<<8448, 256, 0, stream>>>(x, wq, wk, wv, wo, xb, wT, ctab, stab);
  gemm_kernel<<<dim3(32, 8, 3), 256, 0, stream>>>(xb, wT, Qb, Kb, VTb, ctab, stab);
  attn_kernel<<<dim3(32, 16), 256, 0, stream>>>(Qb, Kb, VTb, Ob);
  gemm_final_kernel<<<dim3(64, 8), 128, 0, stream>>>(Ob, wT + 3 * 1048576, out);
}